// Round 2
// baseline (441.558 us; speedup 1.0000x reference)
//
#include <hip/hip_runtime.h>
#include <stdint.h>

#define K_DIM 4096
#define M_TOK 8192
#define N_OUT 4096

typedef int v4i __attribute__((ext_vector_type(4)));

// ---- workspace layout (bytes) ----
// q   : int8 [8192][4096]   @ 0          (33554432)
// tw  : int8 [4096][4096]   @ 33554432   (16777216)
// rs  : float[8192]         @ 50331648   (32768)
// acc : double              @ 50364416   (8)

__device__ __forceinline__ void gload_lds16(const void* g, void* l) {
    auto gp = reinterpret_cast<const __attribute__((address_space(1))) uint32_t*>(
        reinterpret_cast<uintptr_t>(g));
    auto lp = reinterpret_cast<__attribute__((address_space(3))) uint32_t*>(
        reinterpret_cast<uintptr_t>(l));
    __builtin_amdgcn_global_load_lds(gp, lp, 16, 0, 0);
}

// --- per-token activation quantization: q = clip(round(x*s),-128,127), rs = 1/s ---
// also zero-inits the fp64 |w|-sum accumulator (runs before wabs_sum in stream order)
__global__ __launch_bounds__(256) void quant_act(const float* __restrict__ x,
                                                 int8_t* __restrict__ q,
                                                 float* __restrict__ rs,
                                                 double* __restrict__ acc) {
    const int token = blockIdx.x;
    const int t = threadIdx.x;
    if (token == 0 && t == 0) *acc = 0.0;
    const float4* x4 = (const float4*)(x + (size_t)token * K_DIM);
    float4 v[4];
    float m = 0.0f;
#pragma unroll
    for (int r = 0; r < 4; ++r) {
        v[r] = x4[t + 256 * r];
        m = fmaxf(m, fmaxf(fmaxf(fabsf(v[r].x), fabsf(v[r].y)),
                           fmaxf(fabsf(v[r].z), fabsf(v[r].w))));
    }
#pragma unroll
    for (int off = 32; off; off >>= 1) m = fmaxf(m, __shfl_down(m, off, 64));
    __shared__ float wmax[4];
    __shared__ float smax;
    if ((t & 63) == 0) wmax[t >> 6] = m;
    __syncthreads();
    if (t == 0) smax = fmaxf(fmaxf(wmax[0], wmax[1]), fmaxf(wmax[2], wmax[3]));
    __syncthreads();
    const float s = 127.0f / fmaxf(smax, 1e-5f);
    char4* q4 = (char4*)(q + (size_t)token * K_DIM);
#pragma unroll
    for (int r = 0; r < 4; ++r) {
        float4 f = v[r];
        char4 c;
        c.x = (signed char)fminf(fmaxf(rintf(f.x * s), -128.0f), 127.0f);
        c.y = (signed char)fminf(fmaxf(rintf(f.y * s), -128.0f), 127.0f);
        c.z = (signed char)fminf(fmaxf(rintf(f.z * s), -128.0f), 127.0f);
        c.w = (signed char)fminf(fmaxf(rintf(f.w * s), -128.0f), 127.0f);
        q4[t + 256 * r] = c;
    }
    if (t == 0) rs[token] = 1.0f / s;
}

// --- sum |w| into fp64 accumulator ---
__global__ __launch_bounds__(256) void wabs_sum(const float* __restrict__ w,
                                                double* __restrict__ acc) {
    const size_t n4 = (size_t)N_OUT * K_DIM / 4;
    const size_t stride = (size_t)gridDim.x * 256;
    const float4* w4 = (const float4*)w;
    float sum = 0.0f;
    for (size_t j = (size_t)blockIdx.x * 256 + threadIdx.x; j < n4; j += stride) {
        float4 f = w4[j];
        sum += fabsf(f.x) + fabsf(f.y) + fabsf(f.z) + fabsf(f.w);
    }
    double d = (double)sum;
#pragma unroll
    for (int off = 32; off; off >>= 1) d += __shfl_down(d, off, 64);
    __shared__ double wsum[4];
    const int t = threadIdx.x;
    if ((t & 63) == 0) wsum[t >> 6] = d;
    __syncthreads();
    if (t == 0) atomicAdd(acc, wsum[0] + wsum[1] + wsum[2] + wsum[3]);
}

// --- ternarize: tw = clip(round(w*scale_w),-1,1), scale_w = 1/clip(mean|w|,eps) ---
__global__ __launch_bounds__(256) void ternarize(const float* __restrict__ w,
                                                 int8_t* __restrict__ tw,
                                                 const double* __restrict__ acc) {
    const double mean = *acc * (1.0 / ((double)N_OUT * (double)K_DIM));
    const float sw = 1.0f / fmaxf((float)mean, 1e-5f);
    const size_t i = (size_t)blockIdx.x * 256 + threadIdx.x;
    const float4* w4 = (const float4*)w;
    char4* t4 = (char4*)tw;
    float4 f = w4[i];
    char4 c;
    c.x = (signed char)fminf(fmaxf(rintf(f.x * sw), -1.0f), 1.0f);
    c.y = (signed char)fminf(fmaxf(rintf(f.y * sw), -1.0f), 1.0f);
    c.z = (signed char)fminf(fmaxf(rintf(f.z * sw), -1.0f), 1.0f);
    c.w = (signed char)fminf(fmaxf(rintf(f.w * sw), -1.0f), 1.0f);
    t4[i] = c;
}

// --- i8 GEMM: out[m,n] = (sum_k q[m,k]*tw[n,k]) * rs[m] * clip(mean|w|,eps) ---
// 256x256 block tile, BK=64, 512 threads = 8 waves (4x2), wave tile 64x128.
// LDS XOR-swizzle: 16B chunk (row r, chunk c) stored at slot r*4 + (c ^ ((r>>1)&3))
// -> fragment reads hit all 8 bank-quads at 2-way aliasing (free per m136),
//    and staging stays compatible with global_load_lds's lane*16 destination rule.
__global__ __launch_bounds__(512) void gemm_i8(const int8_t* __restrict__ A,
                                               const int8_t* __restrict__ B,
                                               const float* __restrict__ rs,
                                               const double* __restrict__ acc,
                                               float* __restrict__ out) {
    const int bm = blockIdx.y * 256;
    const int bn = blockIdx.x * 256;
    __shared__ int8_t As[256 * 64];
    __shared__ int8_t Bs[256 * 64];
    const int t = threadIdx.x;
    const int lane = t & 63;
    const int wave = t >> 6;
    const int wm = (wave >> 1) * 64;    // 0,64,128,192
    const int wn = (wave & 1) * 128;    // 0,128

    v4i accv[4][8] = {};

    // staging: thread t -> LDS chunk slot t (rows 0..127), swizzled global source col
    const int srow = t >> 2;                                   // 0..127
    const int scol = (((t & 3) ^ ((t >> 3) & 3)) << 4);        // swizzled 16B chunk
    const int8_t* Ag0 = A + (size_t)(bm + srow) * K_DIM + scol;
    const int8_t* Ag1 = Ag0 + (size_t)128 * K_DIM;
    const int8_t* Bg0 = B + (size_t)(bn + srow) * K_DIM + scol;
    const int8_t* Bg1 = Bg0 + (size_t)128 * K_DIM;
    int8_t* lA0 = As + t * 16;
    int8_t* lA1 = As + 8192 + t * 16;
    int8_t* lB0 = Bs + t * 16;
    int8_t* lB1 = Bs + 8192 + t * 16;

    const int fr = lane & 15;                          // fragment row (m or n)
    const int sw16 = (((lane >> 4) ^ ((fr >> 1) & 3)) << 4);  // swizzled K-chunk offset

    for (int k0 = 0; k0 < K_DIM; k0 += 64) {
        gload_lds16(Ag0 + k0, lA0);
        gload_lds16(Ag1 + k0, lA1);
        gload_lds16(Bg0 + k0, lB0);
        gload_lds16(Bg1 + k0, lB1);
        __syncthreads();

        v4i af[4], bf[8];
#pragma unroll
        for (int i = 0; i < 4; ++i)
            af[i] = *(const v4i*)(As + (wm + i * 16 + fr) * 64 + sw16);
#pragma unroll
        for (int j = 0; j < 8; ++j)
            bf[j] = *(const v4i*)(Bs + (wn + j * 16 + fr) * 64 + sw16);
#pragma unroll
        for (int i = 0; i < 4; ++i)
#pragma unroll
            for (int j = 0; j < 8; ++j)
                accv[i][j] = __builtin_amdgcn_mfma_i32_16x16x64_i8(af[i], bf[j], accv[i][j], 0, 0, 0);
        __syncthreads();
    }

    // epilogue: C/D layout col=lane&15, row=(lane>>4)*4+reg
    const double mean = *acc * (1.0 / ((double)N_OUT * (double)K_DIM));
    const float wmean = fmaxf((float)mean, 1e-5f);  // == 1/scale_w
    const int crow0 = (lane >> 4) * 4;
    const int ccol = lane & 15;
#pragma unroll
    for (int i = 0; i < 4; ++i) {
        const int rbase = bm + wm + i * 16 + crow0;
#pragma unroll
        for (int reg = 0; reg < 4; ++reg) {
            const int r = rbase + reg;
            const float scale = rs[r] * wmean;
            float* orow = out + (size_t)r * N_OUT + bn + wn + ccol;
#pragma unroll
            for (int j = 0; j < 8; ++j)
                orow[j * 16] = (float)accv[i][j][reg] * scale;
        }
    }
}

extern "C" void kernel_launch(void* const* d_in, const int* in_sizes, int n_in,
                              void* d_out, int out_size, void* d_ws, size_t ws_size,
                              hipStream_t stream) {
    const float* x = (const float*)d_in[0];
    const float* w = (const float*)d_in[1];
    float* out = (float*)d_out;
    char* ws = (char*)d_ws;
    int8_t* q = (int8_t*)ws;
    int8_t* tw = (int8_t*)(ws + 33554432);
    float* rs = (float*)(ws + 50331648);
    double* acc = (double*)(ws + 50364416);

    hipLaunchKernelGGL(quant_act, dim3(M_TOK), dim3(256), 0, stream, x, q, rs, acc);
    hipLaunchKernelGGL(wabs_sum, dim3(2048), dim3(256), 0, stream, w, acc);
    hipLaunchKernelGGL(ternarize, dim3((N_OUT * (size_t)K_DIM / 4) / 256), dim3(256), 0, stream, w, tw, acc);
    hipLaunchKernelGGL(gemm_i8, dim3(N_OUT / 256, M_TOK / 256), dim3(512), 0, stream, q, tw, rs, acc, out);
}

// Round 3
// 414.406 us; speedup vs baseline: 1.0655x; 1.0655x over previous
//
#include <hip/hip_runtime.h>
#include <stdint.h>

#define K_DIM 4096
#define M_TOK 8192
#define N_OUT 4096

typedef int v4i __attribute__((ext_vector_type(4)));

// ---- workspace layout (bytes) ----
// q   : int8 [8192][4096]   @ 0          (33554432)
// tw  : int8 [4096][4096]   @ 33554432   (16777216)
// rs  : float[8192]         @ 50331648   (32768)
// acc : double              @ 50364416   (8)

__device__ __forceinline__ void gload_lds16(const void* g, void* l) {
    auto gp = reinterpret_cast<const __attribute__((address_space(1))) uint32_t*>(
        reinterpret_cast<uintptr_t>(g));
    auto lp = reinterpret_cast<__attribute__((address_space(3))) uint32_t*>(
        reinterpret_cast<uintptr_t>(l));
    __builtin_amdgcn_global_load_lds(gp, lp, 16, 0, 0);
}

// --- per-token activation quantization: q = clip(round(x*s),-128,127), rs = 1/s ---
// also zero-inits the fp64 |w|-sum accumulator (runs before wabs_sum in stream order)
__global__ __launch_bounds__(256) void quant_act(const float* __restrict__ x,
                                                 int8_t* __restrict__ q,
                                                 float* __restrict__ rs,
                                                 double* __restrict__ acc) {
    const int token = blockIdx.x;
    const int t = threadIdx.x;
    if (token == 0 && t == 0) *acc = 0.0;
    const float4* x4 = (const float4*)(x + (size_t)token * K_DIM);
    float4 v[4];
    float m = 0.0f;
#pragma unroll
    for (int r = 0; r < 4; ++r) {
        v[r] = x4[t + 256 * r];
        m = fmaxf(m, fmaxf(fmaxf(fabsf(v[r].x), fabsf(v[r].y)),
                           fmaxf(fabsf(v[r].z), fabsf(v[r].w))));
    }
#pragma unroll
    for (int off = 32; off; off >>= 1) m = fmaxf(m, __shfl_down(m, off, 64));
    __shared__ float wmax[4];
    __shared__ float smax;
    if ((t & 63) == 0) wmax[t >> 6] = m;
    __syncthreads();
    if (t == 0) smax = fmaxf(fmaxf(wmax[0], wmax[1]), fmaxf(wmax[2], wmax[3]));
    __syncthreads();
    const float s = 127.0f / fmaxf(smax, 1e-5f);
    char4* q4 = (char4*)(q + (size_t)token * K_DIM);
#pragma unroll
    for (int r = 0; r < 4; ++r) {
        float4 f = v[r];
        char4 c;
        c.x = (signed char)fminf(fmaxf(rintf(f.x * s), -128.0f), 127.0f);
        c.y = (signed char)fminf(fmaxf(rintf(f.y * s), -128.0f), 127.0f);
        c.z = (signed char)fminf(fmaxf(rintf(f.z * s), -128.0f), 127.0f);
        c.w = (signed char)fminf(fmaxf(rintf(f.w * s), -128.0f), 127.0f);
        q4[t + 256 * r] = c;
    }
    if (t == 0) rs[token] = 1.0f / s;
}

// --- sum |w| into fp64 accumulator ---
__global__ __launch_bounds__(256) void wabs_sum(const float* __restrict__ w,
                                                double* __restrict__ acc) {
    const size_t n4 = (size_t)N_OUT * K_DIM / 4;
    const size_t stride = (size_t)gridDim.x * 256;
    const float4* w4 = (const float4*)w;
    float sum = 0.0f;
    for (size_t j = (size_t)blockIdx.x * 256 + threadIdx.x; j < n4; j += stride) {
        float4 f = w4[j];
        sum += fabsf(f.x) + fabsf(f.y) + fabsf(f.z) + fabsf(f.w);
    }
    double d = (double)sum;
#pragma unroll
    for (int off = 32; off; off >>= 1) d += __shfl_down(d, off, 64);
    __shared__ double wsum[4];
    const int t = threadIdx.x;
    if ((t & 63) == 0) wsum[t >> 6] = d;
    __syncthreads();
    if (t == 0) atomicAdd(acc, wsum[0] + wsum[1] + wsum[2] + wsum[3]);
}

// --- ternarize: tw = clip(round(w*scale_w),-1,1), scale_w = 1/clip(mean|w|,eps) ---
__global__ __launch_bounds__(256) void ternarize(const float* __restrict__ w,
                                                 int8_t* __restrict__ tw,
                                                 const double* __restrict__ acc) {
    const double mean = *acc * (1.0 / ((double)N_OUT * (double)K_DIM));
    const float sw = 1.0f / fmaxf((float)mean, 1e-5f);
    const size_t i = (size_t)blockIdx.x * 256 + threadIdx.x;
    const float4* w4 = (const float4*)w;
    char4* t4 = (char4*)tw;
    float4 f = w4[i];
    char4 c;
    c.x = (signed char)fminf(fmaxf(rintf(f.x * sw), -1.0f), 1.0f);
    c.y = (signed char)fminf(fmaxf(rintf(f.y * sw), -1.0f), 1.0f);
    c.z = (signed char)fminf(fmaxf(rintf(f.z * sw), -1.0f), 1.0f);
    c.w = (signed char)fminf(fmaxf(rintf(f.w * sw), -1.0f), 1.0f);
    t4[i] = c;
}

// --- i8 GEMM: out[m,n] = (sum_k q[m,k]*tw[n,k]) * rs[m] * clip(mean|w|,eps) ---
// 256x256 block tile, BK=128 (32 K-iters -> half the barrier drains of BK=64),
// 512 threads = 8 waves (4x2), wave tile 64x128, 16x16x64 i8 MFMA.
// LDS rows are 128 B (8 x 16B chunks). XOR swizzle: chunk c of row r lives at
// slot c ^ (r&7). Staging swizzles the SOURCE column (global_load_lds dst must
// stay lane-contiguous); fragment reads hit 8 bank-quads x 2 lanes = 2-way = free.
__global__ __launch_bounds__(512) void gemm_i8(const int8_t* __restrict__ A,
                                               const int8_t* __restrict__ B,
                                               const float* __restrict__ rs,
                                               const double* __restrict__ acc,
                                               float* __restrict__ out) {
    const int bm = blockIdx.y * 256;
    const int bn = blockIdx.x * 256;
    __shared__ int8_t As[256 * 128];
    __shared__ int8_t Bs[256 * 128];
    const int t = threadIdx.x;
    const int lane = t & 63;
    const int wave = t >> 6;
    const int wm = (wave >> 1) * 64;    // 0,64,128,192
    const int wn = (wave & 1) * 128;    // 0,128

    v4i accv[4][8] = {};

    // staging: thread t -> row srow=t>>3 (0..63, +64 per round), swizzled 16B chunk
    const int srow = t >> 3;
    const int scol = (((t & 7) ^ (srow & 7)) << 4);
    const int8_t* Ag = A + (size_t)(bm + srow) * K_DIM + scol;
    const int8_t* Bg = B + (size_t)(bn + srow) * K_DIM + scol;
    int8_t* lA = As + t * 16;
    int8_t* lB = Bs + t * 16;

    const int fr = lane & 15;                 // fragment row (m or n)
    const int c0 = ((((lane >> 4)) ^ (fr & 7)) << 4);  // kstep0 chunk offset
    // kstep1 chunk offset = c0 ^ 64 (chunk index +4, XOR-compatible since q<4)

    for (int k0 = 0; k0 < K_DIM; k0 += 128) {
#pragma unroll
        for (int r = 0; r < 4; ++r) {
            gload_lds16(Ag + k0 + (size_t)(64 * r) * K_DIM, lA + r * 8192);
            gload_lds16(Bg + k0 + (size_t)(64 * r) * K_DIM, lB + r * 8192);
        }
        __syncthreads();

#pragma unroll
        for (int ks = 0; ks < 2; ++ks) {
            const int co = c0 ^ (ks << 6);
            v4i af[4], bf[8];
#pragma unroll
            for (int i = 0; i < 4; ++i)
                af[i] = *(const v4i*)(As + (wm + i * 16 + fr) * 128 + co);
#pragma unroll
            for (int j = 0; j < 8; ++j)
                bf[j] = *(const v4i*)(Bs + (wn + j * 16 + fr) * 128 + co);
#pragma unroll
            for (int i = 0; i < 4; ++i)
#pragma unroll
                for (int j = 0; j < 8; ++j)
                    accv[i][j] = __builtin_amdgcn_mfma_i32_16x16x64_i8(af[i], bf[j], accv[i][j], 0, 0, 0);
        }
        __syncthreads();
    }

    // epilogue: C/D layout col=lane&15, row=(lane>>4)*4+reg
    const double mean = *acc * (1.0 / ((double)N_OUT * (double)K_DIM));
    const float wmean = fmaxf((float)mean, 1e-5f);  // == 1/scale_w
    const int crow0 = (lane >> 4) * 4;
    const int ccol = lane & 15;
#pragma unroll
    for (int i = 0; i < 4; ++i) {
        const int rbase = bm + wm + i * 16 + crow0;
#pragma unroll
        for (int reg = 0; reg < 4; ++reg) {
            const int r = rbase + reg;
            const float scale = rs[r] * wmean;
            float* orow = out + (size_t)r * N_OUT + bn + wn + ccol;
#pragma unroll
            for (int j = 0; j < 8; ++j)
                orow[j * 16] = (float)accv[i][j][reg] * scale;
        }
    }
}

extern "C" void kernel_launch(void* const* d_in, const int* in_sizes, int n_in,
                              void* d_out, int out_size, void* d_ws, size_t ws_size,
                              hipStream_t stream) {
    const float* x = (const float*)d_in[0];
    const float* w = (const float*)d_in[1];
    float* out = (float*)d_out;
    char* ws = (char*)d_ws;
    int8_t* q = (int8_t*)ws;
    int8_t* tw = (int8_t*)(ws + 33554432);
    float* rs = (float*)(ws + 50331648);
    double* acc = (double*)(ws + 50364416);

    hipLaunchKernelGGL(quant_act, dim3(M_TOK), dim3(256), 0, stream, x, q, rs, acc);
    hipLaunchKernelGGL(wabs_sum, dim3(1024), dim3(256), 0, stream, w, acc);
    hipLaunchKernelGGL(ternarize, dim3((N_OUT * (size_t)K_DIM / 4) / 256), dim3(256), 0, stream, w, tw, acc);
    hipLaunchKernelGGL(gemm_i8, dim3(N_OUT / 256, M_TOK / 256), dim3(512), 0, stream, q, tw, rs, acc, out);
}